// Round 8
// baseline (413.997 us; speedup 1.0000x reference)
//
#include <hip/hip_runtime.h>

#define E_TOTAL 50000
#define NTILES  3125      // E_TOTAL / 16, exact
#define NPAIR   1563      // ceil(NTILES / 2) -- one 32-edge block per pair

typedef float f4  __attribute__((ext_vector_type(4)));
typedef short s8v __attribute__((ext_vector_type(8)));   // 8 bf16 bit-patterns (4 VGPRs)
typedef short s4v __attribute__((ext_vector_type(4)));   // 4 bf16 bit-patterns (2 VGPRs)

typedef __attribute__((address_space(3))) unsigned lds_u32;
typedef __attribute__((address_space(1))) const unsigned g_u32;

__device__ __forceinline__ short f2bf(float x){
  unsigned u = __builtin_bit_cast(unsigned, x);
  u += 0x7fffu + ((u >> 16) & 1u);           // RNE
  return (short)(u >> 16);
}
__device__ __forceinline__ float bf2f(short s){
  unsigned u = ((unsigned)(unsigned short)s) << 16;
  return __builtin_bit_cast(float, u);
}
__device__ __forceinline__ float sigm(float x){ return 1.f/(1.f + __expf(-x)); }

// Phase boundary: counted wait (drain only the stage due NOW, keep the
// in-flight next-next stage + input prefetches), then 2-wave barrier.
template<int N>
__device__ __forceinline__ void wtbar(){
  if constexpr (N==0)  asm volatile("s_waitcnt vmcnt(0)"  ::: "memory");
  if constexpr (N==4)  asm volatile("s_waitcnt vmcnt(4)"  ::: "memory");
  if constexpr (N==12) asm volatile("s_waitcnt vmcnt(12)" ::: "memory");
  if constexpr (N==20) asm volatile("s_waitcnt vmcnt(20)" ::: "memory");
  __builtin_amdgcn_s_barrier();
  __builtin_amdgcn_sched_barrier(0);
}

__device__ __forceinline__ s8v load_bfrag(const float* p){
  f4 a = *(const f4*)p;
  f4 b = *(const f4*)(p + 4);
  s8v r;
  r[0]=f2bf(a[0]); r[1]=f2bf(a[1]); r[2]=f2bf(a[2]); r[3]=f2bf(a[3]);
  r[4]=f2bf(b[0]); r[5]=f2bf(b[1]); r[6]=f2bf(b[2]); r[7]=f2bf(b[3]);
  return r;
}

// 8KB-chunk GEMM: D[32 feats x 16 edges] += A(chunk in LDS) @ B
__device__ __forceinline__ void mm2(f4* h2, const s8v* B, const short* buf, int lane){
  const s8v* A = (const s8v*)buf;
  #pragma unroll
  for (int m = 0; m < 2; ++m){
    #pragma unroll
    for (int kk = 0; kk < 4; ++kk){
      s8v af = A[(m*4 + kk)*64 + lane];
      h2[m] = __builtin_amdgcn_mfma_f32_16x16x32_bf16(af, B[kk], h2[m], 0, 0, 0);
    }
  }
}

// Stage one 8KB chunk: 2 waves x 4 instrs x 1KB, global->LDS direct.
__device__ __forceinline__ void stage4(const short* __restrict__ src,
                                       short* dst, int wid, int lane){
  #pragma unroll
  for (int j = 0; j < 4; ++j){
    const short* gsrc = src + wid*2048 + j*512 + lane*8;
    short* ldst = dst + wid*2048 + j*512;       // wave-uniform base
    __builtin_amdgcn_global_load_lds((g_u32*)(const void*)gsrc, (lds_u32*)(void*)ldst, 16, 0, 0);
  }
}

// bf16 param vector (in LDS) -> f4 for (mb, g)
__device__ __forceinline__ f4 ldP(const short* P, int off, int mb, int g){
  s4v t = *(const s4v*)(P + off + mb*16 + g*4);
  f4 r; r[0]=bf2f(t[0]); r[1]=bf2f(t[1]); r[2]=bf2f(t[2]); r[3]=bf2f(t[3]);
  return r;
}
__device__ __forceinline__ f4 addP(const short* P, int off, int mb, int g, s4v c){
  f4 r = ldP(P, off, mb, g);
  r[0]+=bf2f(c[0]); r[1]+=bf2f(c[1]); r[2]+=bf2f(c[2]); r[3]+=bf2f(c[3]);
  return r;
}
__device__ __forceinline__ s4v cvt1(f4 a){
  s4v t; t[0]=f2bf(a[0]); t[1]=f2bf(a[1]); t[2]=f2bf(a[2]); t[3]=f2bf(a[3]);
  return t;
}
__device__ __forceinline__ s8v silu2(const f4& x0, const f4& x1){
  s8v S;
  #pragma unroll
  for (int p = 0; p < 4; ++p){
    float a = x0[p]; S[p]   = f2bf(a * sigm(a));
    float b = x1[p]; S[4+p] = f2bf(b * sigm(b));
  }
  return S;
}

// ---------------------------------------------------------------------------
// Precompute: 14 fragment-ready bf16 A-matrices (A[m][k] = W[k][m], optionally
// W = X@Y fused product), packed so lane reads 16B contiguous per (mblk,kk).
//   mi 0 WqT(nat) | 1 GKT=Wk@Wk1a | 2 GMT=Wv@Wm1a | 3 GKaT=We@Wk1c | 4 GMaT=We@Wm1c
//   mi 5 Wk2T(dlay) | 6 Wm2T(dlay) | 7 WcT(dlay) | 8..10 GKeT[t] | 11..13 GMeT[t]
// ---------------------------------------------------------------------------
__global__ __launch_bounds__(256) void pack_weights(
    const float* __restrict__ Wq, const float* __restrict__ Wk, const float* __restrict__ Wv,
    const float* __restrict__ Wke, const float* __restrict__ Wve, const float* __restrict__ We,
    const float* __restrict__ Wc, const float* __restrict__ Wk1, const float* __restrict__ Wk2,
    const float* __restrict__ Wm1, const float* __restrict__ Wm2,
    short* __restrict__ wsm)
{
  int mi   = blockIdx.x >> 6;
  int elem = ((blockIdx.x & 63) << 8) + threadIdx.x;   // 0..16383
  int p  = elem & 7;
  int l  = (elem >> 3) & 63;
  int kk = (elem >> 9) & 3;
  int mb = elem >> 11;
  int gg = l >> 4;
  int m  = mb*16 + (l & 15);
  bool dlay = (mi == 5) || (mi == 6) || (mi == 7);
  int k = dlay ? (kk*32 + ((p < 4) ? (gg*4 + p) : (16 + gg*4 + (p - 4))))
               : (kk*32 + gg*8 + p);

  const float* X = nullptr; const float* Y = nullptr; const float* W = nullptr;
  switch (mi){
    case 0: W = Wq; break;
    case 1: X = Wk; Y = Wk1;            break;
    case 2: X = Wv; Y = Wm1;            break;
    case 3: X = We; Y = Wk1 + 256*128;  break;
    case 4: X = We; Y = Wm1 + 256*128;  break;
    case 5: W = Wk2; break;
    case 6: W = Wm2; break;
    case 7: W = Wc;  break;
    default:
      if (mi < 11){ X = Wke + (mi-8)*16384;  Y = Wk1 + 128*128; }
      else        { X = Wve + (mi-11)*16384; Y = Wm1 + 128*128; }
  }
  float v;
  if (W){
    v = W[k*128 + m];
  } else {
    v = 0.f;
    for (int j = 0; j < 128; ++j) v += X[k*128 + j] * Y[j*128 + m];
  }
  wsm[(size_t)mi*16384 + elem] = f2bf(v);
}

// biasK[t] = bk@Wk1a + bke[t]@Wk1b + bk1 ; biasM[t] = bv@Wm1a + bve[t]@Wm1b + bm1
__global__ __launch_bounds__(128) void make_biases(
    const float* __restrict__ bk,  const float* __restrict__ bke, const float* __restrict__ bk1,
    const float* __restrict__ bv,  const float* __restrict__ bve, const float* __restrict__ bm1,
    const float* __restrict__ Wk1, const float* __restrict__ Wm1,
    float* __restrict__ wsb)
{
  int b = blockIdx.x;          // 0..2 -> biasK[t], 3..5 -> biasM[t]
  int t = b % 3;
  bool isM = b >= 3;
  int o = threadIdx.x;
  const float* W  = isM ? Wm1 : Wk1;
  const float* b0 = isM ? bv  : bk;
  const float* be = (isM ? bve : bke) + t*128;
  const float* b1 = isM ? bm1 : bk1;
  float v = b1[o];
  for (int j = 0; j < 128; ++j)
    v += b0[j]*W[j*128 + o] + be[j]*W[(128 + j)*128 + o];
  wsb[b*128 + o] = v;
}

// ---------------------------------------------------------------------------
// Main fused kernel. 2 waves/block (32 edges). LDS = 3 x 8KB chunk buffers
// (depth-2 prefetch: stage(p+2) issued during phase p) + 3.5KB bf16 params
// = 27.6KB. 88 phases of 8KB; steady-state wait = vmcnt(4) -- the in-flight
// next-next stage and input prefetches are never drained. 2-wave barriers.
// P layout (bf16 shorts): 0 biasK[3x128] | 384 biasM | 768 bq | 896 bk2 |
//   1024 bm2 | 1152 3*bc | 1280 g_att | 1408 b_att | 1536 g_bn | 1664 b_bn
// ---------------------------------------------------------------------------
__global__ __launch_bounds__(128) void edge_main(
    const float* __restrict__ edge, const float* __restrict__ nlen, const float* __restrict__ nang,
    const float* __restrict__ bq,   const float* __restrict__ bk2,  const float* __restrict__ bm2,
    const float* __restrict__ bc,
    const float* __restrict__ g_att, const float* __restrict__ b_att,
    const float* __restrict__ g_bn,  const float* __restrict__ b_bn,
    const short* __restrict__ wsm,  const float* __restrict__ wsb,
    float* __restrict__ out)
{
  __shared__ short smem[14080];          // 3*4096 chunk bufs + 1792 params = 28160 B
  short* P = smem + 12288;

  const int lane = threadIdx.x & 63;
  const int wid  = threadIdx.x >> 6;
  const int tx   = threadIdx.x;
  const int g = lane >> 4, er = lane & 15;
  int tile = blockIdx.x*2 + wid;
  if (tile > NTILES-1) tile = NTILES-1;  // last pair: both waves tile 3124 (benign dup)
  const size_t e = (size_t)tile*16 + er;
  const float* erow = edge + e*128;

  // ---- prologue: params -> LDS (bf16), input fragments, first two stages ----
  P[        tx] = f2bf(wsb[      tx]);   // biasK t0..2
  P[ 128 +  tx] = f2bf(wsb[128 + tx]);
  P[ 256 +  tx] = f2bf(wsb[256 + tx]);
  P[ 384 +  tx] = f2bf(wsb[384 + tx]);   // biasM t0..2
  P[ 512 +  tx] = f2bf(wsb[512 + tx]);
  P[ 640 +  tx] = f2bf(wsb[640 + tx]);
  P[ 768 +  tx] = f2bf(bq[tx]);
  P[ 896 +  tx] = f2bf(bk2[tx]);
  P[1024 +  tx] = f2bf(bm2[tx]);
  P[1152 +  tx] = f2bf(3.f*bc[tx]);
  P[1280 +  tx] = f2bf(g_att[tx]);
  P[1408 +  tx] = f2bf(b_att[tx]);
  P[1536 +  tx] = f2bf(g_bn[tx]);
  P[1664 +  tx] = f2bf(b_bn[tx]);

  s8v BE[4], BL[4], BA[4];
  #pragma unroll
  for (int kk = 0; kk < 4; ++kk) BE[kk] = load_bfrag(erow + kk*32 + g*8);
  {
    const float* lrow = nlen + e*3*128;
    const float* arow = nang + e*3*128;
    #pragma unroll
    for (int kk = 0; kk < 4; ++kk){
      BL[kk] = load_bfrag(lrow + kk*32 + g*8);
      BA[kk] = load_bfrag(arow + kk*32 + g*8);
    }
  }
  asm volatile("s_waitcnt vmcnt(0) lgkmcnt(0)" ::: "memory");
  __builtin_amdgcn_s_barrier();
  __builtin_amdgcn_sched_barrier(0);

  int bi = 0;
  stage4(wsm + 0*16384 + 0*4096, smem + 0*4096, wid, lane);   // Wq c0 -> buf0
  stage4(wsm + 0*16384 + 1*4096, smem + 1*4096, wid, lane);   // Wq c1 -> buf1

  auto bufp = [&](int i)->short*{ return smem + i*4096; };
  auto advance = [&](const short* s){
    stage4(s, bufp((bi+2)%3), wid, lane);
    bi = (bi+1)%3;
  };

  s4v qb[8], ekb[8], emb[8], gateb[8];
  f4 h[8], gm[8], ev[8];
  s8v S[4];
  #pragma unroll
  for (int mb = 0; mb < 8; ++mb){ f4 z = {0.f,0.f,0.f,0.f}; gm[mb] = z; }

  const short* W_q   = wsm + 0*16384;
  const short* W_gk  = wsm + 1*16384;
  const short* W_gm  = wsm + 2*16384;
  const short* W_gka = wsm + 3*16384;
  const short* W_gma = wsm + 4*16384;
  const short* W_wk2 = wsm + 5*16384;
  const short* W_wm2 = wsm + 6*16384;
  const short* W_wc  = wsm + 7*16384;

  // ---- Wq group -> qb ----
  #pragma unroll
  for (int c = 0; c < 4; ++c){
    wtbar<4>();
    const short* buf = bufp(bi);
    f4 a2[2] = { ldP(P,768,2*c,g), ldP(P,768,2*c+1,g) };
    mm2(a2, BE, buf, lane);
    qb[2*c] = cvt1(a2[0]); qb[2*c+1] = cvt1(a2[1]);
    advance(c < 2 ? W_q + (c+2)*4096 : W_gk + (c-2)*4096);
  }
  // ---- GK group -> ekb ----
  #pragma unroll
  for (int c = 0; c < 4; ++c){
    wtbar<4>();
    const short* buf = bufp(bi);
    f4 a2[2]; { f4 z={0.f,0.f,0.f,0.f}; a2[0]=z; a2[1]=z; }
    mm2(a2, BE, buf, lane);
    ekb[2*c] = cvt1(a2[0]); ekb[2*c+1] = cvt1(a2[1]);
    advance(c < 2 ? W_gk + (c+2)*4096 : W_gm + (c-2)*4096);
  }
  // ---- GM group -> emb ----
  #pragma unroll
  for (int c = 0; c < 4; ++c){
    wtbar<4>();
    const short* buf = bufp(bi);
    f4 a2[2]; { f4 z={0.f,0.f,0.f,0.f}; a2[0]=z; a2[1]=z; }
    mm2(a2, BE, buf, lane);
    emb[2*c] = cvt1(a2[0]); emb[2*c+1] = cvt1(a2[1]);
    advance(c < 2 ? W_gm + (c+2)*4096 : wsm + (size_t)8*16384 + (c-2)*4096);
  }

  #pragma unroll 1
  for (int t = 0; t < 3; ++t){
    const short* W_gke = wsm + (size_t)(8 + t)*16384;
    const short* W_gme = wsm + (size_t)(11 + t)*16384;
    const short* W_nxt = (t < 2) ? wsm + (size_t)(9 + t)*16384 : W_wc;

    // GKe[t]: h = biasK[t] + ekb ; += BL @ GKe
    #pragma unroll
    for (int c = 0; c < 4; ++c){
      wtbar<4>();
      const short* buf = bufp(bi);
      h[2*c]   = addP(P, t*128, 2*c,   g, ekb[2*c]);
      h[2*c+1] = addP(P, t*128, 2*c+1, g, ekb[2*c+1]);
      mm2(&h[2*c], BL, buf, lane);
      advance(c < 2 ? W_gke + (c+2)*4096 : W_gka + (c-2)*4096);
    }
    // GKa: h += BA @ GKa ; silu -> S
    #pragma unroll
    for (int c = 0; c < 4; ++c){
      wtbar<4>();
      const short* buf = bufp(bi);
      mm2(&h[2*c], BA, buf, lane);
      S[c] = silu2(h[2*c], h[2*c+1]);
      advance(c < 2 ? W_gka + (c+2)*4096 : W_wk2 + (c-2)*4096);
    }
    // Wk2: alpha = q .* (S@Wk2 + bk2) / sqrt(C)  (into h)
    #pragma unroll
    for (int c = 0; c < 4; ++c){
      wtbar<4>();
      const short* buf = bufp(bi);
      f4 a2[2] = { ldP(P,896,2*c,g), ldP(P,896,2*c+1,g) };
      mm2(a2, S, buf, lane);
      #pragma unroll
      for (int r = 0; r < 4; ++r){
        h[2*c][r]   = bf2f(qb[2*c][r])   * a2[0][r] * 0.08838834764831845f;
        h[2*c+1][r] = bf2f(qb[2*c+1][r]) * a2[1][r] * 0.08838834764831845f;
      }
      advance(c < 2 ? W_wk2 + (c+2)*4096 : W_gme + (c-2)*4096);
    }
    // LN over h ; gate
    {
      float sm = 0.f, ssq = 0.f;
      #pragma unroll
      for (int mb = 0; mb < 8; ++mb){
        #pragma unroll
        for (int r = 0; r < 4; ++r){ sm += h[mb][r]; ssq += h[mb][r]*h[mb][r]; }
      }
      sm  += __shfl_xor(sm, 16);  sm  += __shfl_xor(sm, 32);
      ssq += __shfl_xor(ssq, 16); ssq += __shfl_xor(ssq, 32);
      float mean = sm * (1.f/128.f);
      float rstd = rsqrtf(ssq * (1.f/128.f) - mean*mean + 1e-5f);
      #pragma unroll
      for (int mb = 0; mb < 8; ++mb){
        f4 ga = ldP(P,1280,mb,g), bb = ldP(P,1408,mb,g);
        s4v t4;
        #pragma unroll
        for (int r = 0; r < 4; ++r)
          t4[r] = f2bf(sigm((h[mb][r] - mean)*rstd*ga[r] + bb[r]));
        gateb[mb] = t4;
      }
    }
    // GMe[t]: h = biasM[t] + emb ; += BL @ GMe
    #pragma unroll
    for (int c = 0; c < 4; ++c){
      wtbar<4>();
      const short* buf = bufp(bi);
      h[2*c]   = addP(P, 384 + t*128, 2*c,   g, emb[2*c]);
      h[2*c+1] = addP(P, 384 + t*128, 2*c+1, g, emb[2*c+1]);
      mm2(&h[2*c], BL, buf, lane);
      advance(c < 2 ? W_gme + (c+2)*4096 : W_gma + (c-2)*4096);
    }
    // GMa: h += BA @ GMa ; silu -> S ; at c3: prefetch next BL/BA or ev
    #pragma unroll
    for (int c = 0; c < 4; ++c){
      wtbar<4>();
      const short* buf = bufp(bi);
      mm2(&h[2*c], BA, buf, lane);
      S[c] = silu2(h[2*c], h[2*c+1]);
      if (c == 3){
        if (t < 2){
          const float* lrow = nlen + (e*3 + t + 1)*128;
          const float* arow = nang + (e*3 + t + 1)*128;
          #pragma unroll
          for (int kk = 0; kk < 4; ++kk){
            BL[kk] = load_bfrag(lrow + kk*32 + g*8);
            BA[kk] = load_bfrag(arow + kk*32 + g*8);
          }
        } else {
          #pragma unroll
          for (int mb = 0; mb < 8; ++mb) ev[mb] = *(const f4*)(erow + mb*16 + g*4);
        }
      }
      advance(c < 2 ? W_gma + (c+2)*4096 : W_wm2 + (c-2)*4096);
    }
    // Wm2: ma = S@Wm2 + bm2 ; gm += gate .* ma
    // waits: c0 must not drain the input prefetches (16 or 8 in flight)
    #pragma unroll
    for (int c = 0; c < 4; ++c){
      if (c == 0){ if (t < 2) wtbar<20>(); else wtbar<12>(); }
      else wtbar<4>();
      const short* buf = bufp(bi);
      f4 a2[2] = { ldP(P,1024,2*c,g), ldP(P,1024,2*c+1,g) };
      mm2(a2, S, buf, lane);
      #pragma unroll
      for (int r = 0; r < 4; ++r){
        gm[2*c][r]   += a2[0][r] * bf2f(gateb[2*c][r]);
        gm[2*c+1][r] += a2[1][r] * bf2f(gateb[2*c+1][r]);
      }
      advance(c < 2 ? W_wm2 + (c+2)*4096 : W_nxt + (c-2)*4096);
    }
  }

  // ---- Wc group: o = gm@Wc + 3bc (into h) ----
  s8v GF[4];
  #pragma unroll
  for (int kk = 0; kk < 4; ++kk){
    #pragma unroll
    for (int p = 0; p < 4; ++p){
      GF[kk][p]   = f2bf(gm[2*kk][p]);
      GF[kk][4+p] = f2bf(gm[2*kk+1][p]);
    }
  }
  #pragma unroll
  for (int c = 0; c < 4; ++c){
    if (c == 3) wtbar<0>(); else wtbar<4>();
    const short* buf = bufp(bi);
    f4 a2[2] = { ldP(P,1152,2*c,g), ldP(P,1152,2*c+1,g) };
    mm2(a2, GF, buf, lane);
    h[2*c] = a2[0]; h[2*c+1] = a2[1];
    if (c < 2) advance(W_wc + (c+2)*4096);
    else       bi = (bi+1)%3;
  }

  // ---- LN ; softplus(edge + .) ; store ----
  float sm = 0.f, ssq = 0.f;
  #pragma unroll
  for (int mb = 0; mb < 8; ++mb){
    #pragma unroll
    for (int r = 0; r < 4; ++r){ sm += h[mb][r]; ssq += h[mb][r]*h[mb][r]; }
  }
  sm  += __shfl_xor(sm, 16);  sm  += __shfl_xor(sm, 32);
  ssq += __shfl_xor(ssq, 16); ssq += __shfl_xor(ssq, 32);
  float mean = sm * (1.f/128.f);
  float rstd = rsqrtf(ssq * (1.f/128.f) - mean*mean + 1e-5f);

  #pragma unroll
  for (int mb = 0; mb < 8; ++mb){
    f4 gv = ldP(P,1536,mb,g), bv = ldP(P,1664,mb,g);
    f4 o;
    #pragma unroll
    for (int r = 0; r < 4; ++r){
      float x = ev[mb][r] + (h[mb][r] - mean)*rstd*gv[r] + bv[r];
      o[r] = (x > 20.f) ? x : log1pf(__expf(x));
    }
    *(f4*)(out + e*128 + mb*16 + g*4) = o;
  }
}

extern "C" void kernel_launch(void* const* d_in, const int* in_sizes, int n_in,
                              void* d_out, int out_size, void* d_ws, size_t ws_size,
                              hipStream_t stream)
{
  const float* edge = (const float*)d_in[0];
  const float* nlen = (const float*)d_in[1];
  const float* nang = (const float*)d_in[2];
  const float* Wq  = (const float*)d_in[3];
  const float* bq  = (const float*)d_in[4];
  const float* Wk  = (const float*)d_in[5];
  const float* bk  = (const float*)d_in[6];
  const float* Wv  = (const float*)d_in[7];
  const float* bv  = (const float*)d_in[8];
  const float* Wke = (const float*)d_in[9];
  const float* bke = (const float*)d_in[10];
  const float* Wve = (const float*)d_in[11];
  const float* bve = (const float*)d_in[12];
  const float* We  = (const float*)d_in[13];
  const float* Wc  = (const float*)d_in[14];
  const float* bc  = (const float*)d_in[15];
  const float* Wk1 = (const float*)d_in[16];
  const float* bk1 = (const float*)d_in[17];
  const float* Wk2 = (const float*)d_in[18];
  const float* bk2 = (const float*)d_in[19];
  const float* Wm1 = (const float*)d_in[20];
  const float* bm1 = (const float*)d_in[21];
  const float* Wm2 = (const float*)d_in[22];
  const float* bm2 = (const float*)d_in[23];
  const float* g_att = (const float*)d_in[24];
  const float* b_att = (const float*)d_in[25];
  const float* g_bn  = (const float*)d_in[26];
  const float* b_bn  = (const float*)d_in[27];

  // ws layout: 14 packed bf16 matrices (16384 shorts each) + 6*128 f32 biases
  short* wsm = (short*)d_ws;
  float* wsb = (float*)((char*)d_ws + (size_t)14*16384*2);

  pack_weights<<<dim3(14*64), dim3(256), 0, stream>>>(
      Wq, Wk, Wv, Wke, Wve, We, Wc, Wk1, Wk2, Wm1, Wm2, wsm);
  make_biases<<<dim3(6), dim3(128), 0, stream>>>(
      bk, bke, bk1, bv, bve, bm1, Wk1, Wm1, wsb);
  edge_main<<<dim3(NPAIR), dim3(128), 0, stream>>>(
      edge, nlen, nang, bq, bk2, bm2, bc, g_att, b_att, g_bn, b_bn,
      wsm, wsb, (float*)d_out);
}